// Round 3
// baseline (352.712 us; speedup 1.0000x reference)
//
#include <hip/hip_runtime.h>

// out = relu(concat(nf, prompt[bidx]) @ W1 + b1) @ W2 + b2
//   P2[g]  = prompt[g] @ W1[512:,:] + b1       (tiny GEMM, 1024x512)
//   fused: acc = P2[bidx]; acc += nf @ W1[:512]; h=relu(acc) -> LDS;
//          out = h @ W2 + b2                   (h never touches HBM)

#define N_NODES   100000

typedef __bf16 bf16x8 __attribute__((ext_vector_type(8)));
typedef float  f32x4  __attribute__((ext_vector_type(4)));
typedef unsigned short ushort_t;

__device__ __forceinline__ ushort_t f2bf(float f) {
  __bf16 b = (__bf16)f;
  return __builtin_bit_cast(unsigned short, b);
}

__device__ __forceinline__ void gload_lds16(const void* g, void* l) {
  __builtin_amdgcn_global_load_lds(
      (const __attribute__((address_space(1))) void*)g,
      (__attribute__((address_space(3))) void*)l, 16, 0, 0);
}

__device__ __forceinline__ void barrier_nodrain() {
  asm volatile("s_waitcnt lgkmcnt(0)" ::: "memory");
  __builtin_amdgcn_s_barrier();
  __builtin_amdgcn_sched_barrier(0);
}

// ---------------- prep: bf16 conversions + weight transposes ----------------
__global__ void prep_kernel(const float* __restrict__ gp, const float* __restrict__ W1,
                            const float* __restrict__ W2, ushort_t* __restrict__ prm,
                            ushort_t* __restrict__ W1T, ushort_t* __restrict__ W2T) {
  int i = blockIdx.x * 256 + threadIdx.x;
  if (i < 524288) {
    prm[i] = f2bf(gp[i]);                       // prm[g*512+k]
  } else if (i < 1048576) {
    int j = i - 524288;
    int n = j >> 10, k = j & 1023;
    W1T[j] = f2bf(W1[k * 512 + n]);             // W1T[n*1024+k]
  } else if (i < 1310720) {
    int j = i - 1048576;
    int n = j >> 9, k = j & 511;
    W2T[j] = f2bf(W2[k * 512 + n]);             // W2T[n*512+k]
  }
}

// ---------------- P2[g][n] = prm[g] @ W1b + bias1[n] ----------------
__global__ __launch_bounds__(256, 2) void p2_kernel(
    const ushort_t* __restrict__ prm, const ushort_t* __restrict__ W1T,
    const float* __restrict__ bias1, float* __restrict__ P2) {
  __shared__ ushort_t sA[128 * 64];
  __shared__ ushort_t sB[128 * 64];
  const int tid = threadIdx.x, lane = tid & 63, wid = tid >> 6;
  const int m0 = (blockIdx.x >> 2) * 128, n0 = (blockIdx.x & 3) * 128;

  const ushort_t* pA[4]; const ushort_t* pB[4]; int ldsW[4];
#pragma unroll
  for (int s = 0; s < 4; ++s) {
    int q = wid * 256 + s * 64 + lane;
    int row = q >> 3;
    int cw = (q & 7) ^ (row & 7);
    pA[s] = prm + (size_t)(m0 + row) * 512 + cw * 8;
    pB[s] = W1T + (size_t)(n0 + row) * 1024 + 512 + cw * 8;
    ldsW[s] = (wid * 256 + s * 64) * 8;
  }
  f32x4 acc[4][4];
#pragma unroll
  for (int i = 0; i < 4; ++i)
#pragma unroll
    for (int j = 0; j < 4; ++j) acc[i][j] = {0.f, 0.f, 0.f, 0.f};
  const int wm = (wid >> 1) * 64, wn = (wid & 1) * 64;
  const int lr = lane >> 4, lc = lane & 15;

  for (int kt = 0; kt < 8; ++kt) {
#pragma unroll
    for (int s = 0; s < 4; ++s) {
      gload_lds16(pA[s], &sA[ldsW[s]]); pA[s] += 64;
      gload_lds16(pB[s], &sB[ldsW[s]]); pB[s] += 64;
    }
    __syncthreads();
#pragma unroll
    for (int kk = 0; kk < 2; ++kk) {
      bf16x8 af[4], bfr[4];
#pragma unroll
      for (int i = 0; i < 4; ++i) {
        int row = wm + i * 16 + lc;
        int cp = (kk * 4 + lr) ^ (row & 7);
        af[i] = *(const bf16x8*)&sA[row * 64 + cp * 8];
      }
#pragma unroll
      for (int j = 0; j < 4; ++j) {
        int col = wn + j * 16 + lc;
        int cp = (kk * 4 + lr) ^ (col & 7);
        bfr[j] = *(const bf16x8*)&sB[col * 64 + cp * 8];
      }
#pragma unroll
      for (int i = 0; i < 4; ++i)
#pragma unroll
        for (int j = 0; j < 4; ++j)
          acc[i][j] = __builtin_amdgcn_mfma_f32_16x16x32_bf16(af[i], bfr[j], acc[i][j], 0, 0, 0);
    }
    __syncthreads();
  }
#pragma unroll
  for (int j = 0; j < 4; ++j) {
    int col = n0 + wn + j * 16 + lc;
    float bv = bias1[col];
#pragma unroll
    for (int i = 0; i < 4; ++i)
#pragma unroll
      for (int r = 0; r < 4; ++r) {
        int row = m0 + wm + i * 16 + lr * 4 + r;
        P2[(size_t)row * 512 + col] = acc[i][j][r] + bv;
      }
  }
}

// ---------------- fused ----------------
__global__ __launch_bounds__(512, 2) void fused_kernel(
    const float* __restrict__ nf, const int* __restrict__ bidx,
    const ushort_t* __restrict__ W1T, const float* __restrict__ P2,
    const ushort_t* __restrict__ W2T, const float* __restrict__ bias2,
    float* __restrict__ out) {
  __shared__ ushort_t sA[2][64 * 64];   // 2 x 8 KB A-panels, chunk-swizzled
  __shared__ ushort_t sH[64 * 512];     // 64 KB h tile, swizzled; total 80 KB

  const int tid = threadIdx.x;
  const int lane = tid & 63;
  const int cg = tid >> 6;              // wave = col-group (64 cols)
  const int lc = lane & 15, lr = lane >> 4;
  const int m0 = blockIdx.x * 64;

  // A staging: 1 chunk (8 bf16) per thread per panel, swizzled via source addr
  const int arow = tid >> 3;
  const int aclog = (tid & 7) ^ (arow & 7);
  int arowg = m0 + arow; if (arowg > N_NODES - 1) arowg = N_NODES - 1;
  const float* abase = nf + (size_t)arowg * 512 + aclog * 8;

  // stage panel 0
  {
    float4 x = *(const float4*)(abase);
    float4 y = *(const float4*)(abase + 4);
    bf16x8 v;
    v[0] = (__bf16)x.x; v[1] = (__bf16)x.y; v[2] = (__bf16)x.z; v[3] = (__bf16)x.w;
    v[4] = (__bf16)y.x; v[5] = (__bf16)y.y; v[6] = (__bf16)y.z; v[7] = (__bf16)y.w;
    *(bf16x8*)&sA[0][tid * 8] = v;
  }

  // acc init = P2[bidx[row]][col]  (gather overlaps staging latency)
  f32x4 acc[4][4];
#pragma unroll
  for (int i = 0; i < 4; ++i) {
#pragma unroll
    for (int r = 0; r < 4; ++r) {
      int rowg = m0 + i * 16 + lr * 4 + r;
      if (rowg > N_NODES - 1) rowg = N_NODES - 1;
      int g = bidx[rowg];
      const float* p2r = P2 + (size_t)g * 512 + cg * 64 + lc;
#pragma unroll
      for (int j = 0; j < 4; ++j) acc[i][j][r] = p2r[j * 16];
    }
  }

  // B1 fragment base: row (=out col) cg*64 + j*16 + lc, k offset lr*8
  const ushort_t* wbase = W1T + (size_t)(cg * 64 + lc) * 1024 + lr * 8;
  bf16x8 bcur[4];
#pragma unroll
  for (int j = 0; j < 4; ++j)
    bcur[j] = *(const bf16x8*)(wbase + (size_t)j * 16384);   // kt=0, kk=0

  barrier_nodrain();   // publishes panel 0; bcur/acc loads stay in flight

  // ---- GEMM1: 8 kt x 2 kk, software-pipelined B frags + A panel dbuf ----
#pragma unroll
  for (int kt = 0; kt < 8; ++kt) {
    float4 ax, ay;
    if (kt < 7) {
      ax = *(const float4*)(abase + (kt + 1) * 64);
      ay = *(const float4*)(abase + (kt + 1) * 64 + 4);
    }
    const ushort_t* buf = sA[kt & 1];
    // prefetch kk=1 frags
    bf16x8 bnxt[4];
#pragma unroll
    for (int j = 0; j < 4; ++j)
      bnxt[j] = *(const bf16x8*)(wbase + (size_t)j * 16384 + kt * 64 + 32);
    // kk = 0
#pragma unroll
    for (int i = 0; i < 4; ++i) {
      int row = i * 16 + lc;
      int phys = lr ^ (row & 7);
      bf16x8 a = *(const bf16x8*)&buf[row * 64 + phys * 8];
#pragma unroll
      for (int j = 0; j < 4; ++j)
        acc[i][j] = __builtin_amdgcn_mfma_f32_16x16x32_bf16(a, bcur[j], acc[i][j], 0, 0, 0);
    }
    // prefetch next kt's kk=0 frags
    if (kt < 7) {
#pragma unroll
      for (int j = 0; j < 4; ++j)
        bcur[j] = *(const bf16x8*)(wbase + (size_t)j * 16384 + (kt + 1) * 64);
    }
    // kk = 1
#pragma unroll
    for (int i = 0; i < 4; ++i) {
      int row = i * 16 + lc;
      int phys = (4 + lr) ^ (row & 7);
      bf16x8 a = *(const bf16x8*)&buf[row * 64 + phys * 8];
#pragma unroll
      for (int j = 0; j < 4; ++j)
        acc[i][j] = __builtin_amdgcn_mfma_f32_16x16x32_bf16(a, bnxt[j], acc[i][j], 0, 0, 0);
    }
    // publish next A panel
    if (kt < 7) {
      bf16x8 v;
      v[0] = (__bf16)ax.x; v[1] = (__bf16)ax.y; v[2] = (__bf16)ax.z; v[3] = (__bf16)ax.w;
      v[4] = (__bf16)ay.x; v[5] = (__bf16)ay.y; v[6] = (__bf16)ay.z; v[7] = (__bf16)ay.w;
      *(bf16x8*)&sA[(kt + 1) & 1][tid * 8] = v;
      barrier_nodrain();
    }
  }

  // ---- epi1: h = relu(acc) -> sH (bf16, swizzled) ----
#pragma unroll
  for (int i = 0; i < 4; ++i) {
#pragma unroll
    for (int r = 0; r < 4; ++r) {
      int row = i * 16 + lr * 4 + r;
#pragma unroll
      for (int j = 0; j < 4; ++j) {
        int col = cg * 64 + j * 16 + lc;
        float v = fmaxf(acc[i][j][r], 0.f);
        int c = col >> 3;
        int phys = (c & 48) | ((c ^ row) & 15);
        *(__bf16*)((char*)sH + row * 1024 + phys * 16 + (col & 7) * 2) = (__bf16)v;
      }
    }
  }
  barrier_nodrain();

  // ---- GEMM2: acc reused; no barriers, compiler free to pipeline ----
#pragma unroll
  for (int i = 0; i < 4; ++i)
#pragma unroll
    for (int j = 0; j < 4; ++j) acc[i][j] = {0.f, 0.f, 0.f, 0.f};

  const ushort_t* w2base = W2T + (size_t)(cg * 64 + lc) * 512 + lr * 8;
#pragma unroll
  for (int kk = 0; kk < 16; ++kk) {
    bf16x8 b2f[4];
#pragma unroll
    for (int j = 0; j < 4; ++j)
      b2f[j] = *(const bf16x8*)(w2base + (size_t)j * 8192 + kk * 32);
#pragma unroll
    for (int i = 0; i < 4; ++i) {
      int row = i * 16 + lc;
      int c = kk * 4 + lr;
      int phys = (c & 48) | ((c ^ row) & 15);
      bf16x8 a2 = *(const bf16x8*)&sH[row * 512 + phys * 8];
#pragma unroll
      for (int j = 0; j < 4; ++j)
        acc[i][j] = __builtin_amdgcn_mfma_f32_16x16x32_bf16(a2, b2f[j], acc[i][j], 0, 0, 0);
    }
  }

  // ---- epi2: out = acc + bias2 ----
#pragma unroll
  for (int j = 0; j < 4; ++j) {
    int col = cg * 64 + j * 16 + lc;
    float bv = bias2[col];
#pragma unroll
    for (int i = 0; i < 4; ++i)
#pragma unroll
      for (int r = 0; r < 4; ++r) {
        int rowg = m0 + i * 16 + lr * 4 + r;
        if (rowg < N_NODES)
          out[(size_t)rowg * 512 + col] = acc[i][j][r] + bv;
      }
  }
}

extern "C" void kernel_launch(void* const* d_in, const int* in_sizes, int n_in,
                              void* d_out, int out_size, void* d_ws, size_t ws_size,
                              hipStream_t stream) {
  const float* nf   = (const float*)d_in[0];
  const float* gp   = (const float*)d_in[1];
  const int*   bidx = (const int*)d_in[2];
  const float* W1   = (const float*)d_in[3];
  const float* b1   = (const float*)d_in[4];
  const float* W2   = (const float*)d_in[5];
  const float* b2   = (const float*)d_in[6];
  float* out = (float*)d_out;

  char* ws = (char*)d_ws;
  ushort_t* prm = (ushort_t*)ws;                    // 1,048,576 B
  ushort_t* W1T = (ushort_t*)(ws + 1048576);        // 1,048,576 B
  ushort_t* W2T = (ushort_t*)(ws + 2097152);        //   524,288 B
  float*    P2  = (float*)   (ws + 2621440);        // 2,097,152 B

  prep_kernel<<<5120, 256, 0, stream>>>(gp, W1, W2, prm, W1T, W2T);
  p2_kernel<<<32, 256, 0, stream>>>(prm, W1T, b1, P2);
  fused_kernel<<<(N_NODES + 63) / 64, 512, 0, stream>>>(nf, bidx, W1T, P2, W2T, b2, out);
}